// Round 3
// baseline (417.841 us; speedup 1.0000x reference)
//
#include <hip/hip_runtime.h>
#include <hip/hip_bf16.h>

#define HIDDEN 768
#define HEADS 12
#define HEAD_DIM 64
#define BATCH 128
#define SEQ 196
#define M_TOT (BATCH * SEQ)   /* 25088 */
#define QKV_N (3 * HIDDEN)    /* 2304  */

typedef __attribute__((ext_vector_type(8))) short bf16x8;
typedef __attribute__((ext_vector_type(8))) unsigned short u16x8;
typedef __attribute__((ext_vector_type(4))) float f32x4;

// round-to-nearest-even f32 -> bf16 (bit pattern)
__device__ __forceinline__ unsigned short f2bf(float f) {
    unsigned int u = __builtin_bit_cast(unsigned int, f);
    unsigned int r = (u + 0x7fffu + ((u >> 16) & 1u)) >> 16;
    return (unsigned short)r;
}

__device__ __forceinline__ ushort4 cvt4(float4 v) {
    ushort4 o;
    o.x = f2bf(v.x); o.y = f2bf(v.y); o.z = f2bf(v.z); o.w = f2bf(v.w);
    return o;
}

// ---------------------------------------------------------------------------
// prep: cast x -> bf16; build fused Wqkv [2304,768] bf16 (rows: Wq|Wk|Wv);
// cast Wp -> bf16; fuse biases [2304] f32.
// ---------------------------------------------------------------------------
__global__ __launch_bounds__(256) void prep_kernel(
    const float* __restrict__ x,
    const float* __restrict__ Wq, const float* __restrict__ Wk,
    const float* __restrict__ Wv, const float* __restrict__ Wp,
    const float* __restrict__ bq, const float* __restrict__ bk,
    const float* __restrict__ bv,
    unsigned short* __restrict__ xb, unsigned short* __restrict__ wqkv,
    unsigned short* __restrict__ wpb, float* __restrict__ biasq)
{
    const long long NX = (long long)M_TOT * HIDDEN / 4;        // 4816896
    const long long NQ = NX + (long long)QKV_N * HIDDEN / 4;   // +442368
    const long long NP = NQ + (long long)HIDDEN * HIDDEN / 4;  // +147456
    const long long NB = NP + QKV_N / 4;                       // +576
    long long tid = (long long)blockIdx.x * 256 + threadIdx.x;
    if (tid < NX) {
        float4 v = ((const float4*)x)[tid];
        ((ushort4*)xb)[tid] = cvt4(v);
    } else if (tid < NQ) {
        int i = (int)(tid - NX);
        int e = i * 4;
        int row = e / HIDDEN, col = e % HIDDEN;
        const float* s = (row < HIDDEN) ? (Wq + (size_t)row * HIDDEN + col)
                       : (row < 2 * HIDDEN) ? (Wk + (size_t)(row - HIDDEN) * HIDDEN + col)
                       : (Wv + (size_t)(row - 2 * HIDDEN) * HIDDEN + col);
        ((ushort4*)wqkv)[i] = cvt4(*(const float4*)s);
    } else if (tid < NP) {
        int i = (int)(tid - NQ);
        ((ushort4*)wpb)[i] = cvt4(((const float4*)Wp)[i]);
    } else if (tid < NB) {
        int i = (int)(tid - NP);
        int e = i * 4;
        const float* s = (e < HIDDEN) ? (bq + e)
                       : (e < 2 * HIDDEN) ? (bk + (e - HIDDEN))
                       : (bv + (e - 2 * HIDDEN));
        *(float4*)(biasq + e) = *(const float4*)s;
    }
}

// ---------------------------------------------------------------------------
// gemm256 v3: 256x256 tile, 8 waves (2M x 4N), wave tile 128x64, acc[8][4].
// C[M,Ncols] = A[M,768] * B[Ncols,768]^T + bias.
//
// v3 structure (fixes R2's Bf-corruption bug; kills R1's lockstep stalls):
//  * B direct global->regs, refilled ONLY after ph3's MFMA cluster (all 8
//    loads, j=0 first). j-outer MFMA nest -> Bf[0] first-needed: ~240cyc
//    cover >= L2 latency. B is L2-resident via col-major XCD chunking.
//  * A in LDS, 4 x 32KB buffers, staged ~1.5 tiles ahead via global_load_lds
//    (linear dest, pre-swizzled source; T2 XOR on reads).
//  * ONE barrier per K-tile (no intra-tile LDS hazards: waves read buf kt,
//    staging writes buf kt+2 == long-dead kt-2). No per-phase lgkmcnt(0);
//    compiler emits counted lgkm waits and pipelines across phases freely.
//  * Issue-order discipline (in-order vmcnt retirement): per tile issue
//    [B(kt+1) x8, then A(kt+2) x4], pinned by sched_barrier(0) fences.
//    => ph0's compiler B-wait is vmcnt(4); boundary asm wait vmcnt(12)
//    retires exactly A(kt+1). Queue never drains until the tail.
//  * No setprio (it is a scheduling fence; would re-serialize the phases).
// Epilogue: per-wave LDS staging -> full-cache-line b128 stores (R1-verified).
// ---------------------------------------------------------------------------
template <bool OUT_BF16>
__global__ __launch_bounds__(512, 2) void gemm256(
    const unsigned short* __restrict__ A,
    const unsigned short* __restrict__ B,
    const float* __restrict__ bias,
    void* __restrict__ C, const int Ncols)
{
    __shared__ __align__(16) unsigned short SMEM[65536];  // 4 x 32KB A bufs
    const int t = threadIdx.x, w = t >> 6, lane = t & 63;
    const int quad = lane >> 4, l15 = lane & 15;
    const int wm = w >> 2, wn = w & 3;

    // ---- COLUMN-major linearization + bijective XCD chunking (m204) ----
    const int gy = gridDim.y;                                  // m-tiles (98)
    const int nwg = gridDim.x * gy;
    const int orig = blockIdx.y * gridDim.x + blockIdx.x;
    const int qq = nwg >> 3, rr2 = nwg & 7;
    const int xcd = orig & 7, loc = orig >> 3;
    const int pos = (xcd < rr2 ? xcd * (qq + 1) : rr2 * (qq + 1) + (xcd - rr2) * qq) + loc;
    const int m0 = (pos % gy) * 256;
    const int n0 = (pos / gy) * 256;

    // ---- A staging: linear LDS dest, inverse-swizzled global source ----
    const int row64 = t >> 3, slot = t & 7;              // 64 rows / issue
    const int ksw = (slot ^ (row64 & 7)) << 3;           // pre-swizzled k-col
    const unsigned short* Ag = A + (size_t)m0 * HIDDEN + ksw;
    const int ldsw = (w << 3) * 64;                      // wave-uniform base

#define STAGEA(bb, tt, pp)                                                          \
    __builtin_amdgcn_global_load_lds(                                               \
        (__attribute__((address_space(1))) void*)(Ag + (size_t)((pp) * 64 + row64) * HIDDEN + (tt) * 64), \
        (__attribute__((address_space(3))) void*)(SMEM + (bb) * 16384 + (pp) * 4096 + ldsw), 16, 0, 0)

    // ---- A fragment read pointers (T2 swizzled: slot q -> q ^ (row&7)) ----
    const int sw = l15 & 7;                 // == row&7 for all frag rows
    const int s0 = (quad ^ sw) << 3;        // k-half 0, k-slot = quad
    const int s1 = ((quad + 4) ^ sw) << 3;  // k-half 1, k-slot = quad+4
    const unsigned short* pa = SMEM + (wm * 128 + l15) * 64;

    // ---- B direct-from-global fragment base ----
    // frag (j,h): row n0 + wn*64 + j*16 + l15, k = kt*64 + h*32 + quad*8 ..
    const unsigned short* Bgf = B + (size_t)(n0 + wn * 64 + l15) * HIDDEN + quad * 8;

    f32x4 acc[8][4] = {};
    bf16x8 Bf[4][2];

    // ---- prologue: queue order [A(0)x4 | B(0)x8 | A(1)x4], retire A(0) ----
#pragma unroll
    for (int p = 0; p < 4; ++p) STAGEA(0, 0, p);
    __builtin_amdgcn_sched_barrier(0);
#pragma unroll
    for (int j = 0; j < 4; ++j) {
        Bf[j][0] = *(const bf16x8*)(Bgf + j * 12288);
        Bf[j][1] = *(const bf16x8*)(Bgf + j * 12288 + 32);
    }
    __builtin_amdgcn_sched_barrier(0);
#pragma unroll
    for (int p = 0; p < 4; ++p) STAGEA(1, 1, p);
    asm volatile("s_waitcnt vmcnt(12)" ::: "memory");
    __builtin_amdgcn_s_barrier();
    __builtin_amdgcn_sched_barrier(0);

    // ---- K loop: 12 tiles of BK=64, fully unrolled, 1 barrier/tile ----
#pragma unroll
    for (int kt = 0; kt < 12; ++kt) {
        const unsigned short* pab = pa + (kt & 3) * 16384;

#pragma unroll
        for (int ph = 0; ph < 4; ++ph) {
            const int ib = ph * 2;
            bf16x8 Af[2][2];
            Af[0][0] = *(const bf16x8*)(pab + ib * 1024 + s0);
            Af[0][1] = *(const bf16x8*)(pab + ib * 1024 + s1);
            Af[1][0] = *(const bf16x8*)(pab + ib * 1024 + 1024 + s0);
            Af[1][1] = *(const bf16x8*)(pab + ib * 1024 + 1024 + s1);
#pragma unroll
            for (int j = 0; j < 4; ++j)
#pragma unroll
                for (int i = 0; i < 2; ++i) {
                    acc[ib + i][j] = __builtin_amdgcn_mfma_f32_16x16x32_bf16(
                        Af[i][0], Bf[j][0], acc[ib + i][j], 0, 0, 0);
                    acc[ib + i][j] = __builtin_amdgcn_mfma_f32_16x16x32_bf16(
                        Af[i][1], Bf[j][1], acc[ib + i][j], 0, 0, 0);
                }
        }

        if (kt < 11) {
            // B refill for kt+1 (post-last-use; j=0 issued first).
#pragma unroll
            for (int j = 0; j < 4; ++j) {
                Bf[j][0] = *(const bf16x8*)(Bgf + j * 12288 + (kt + 1) * 64);
                Bf[j][1] = *(const bf16x8*)(Bgf + j * 12288 + (kt + 1) * 64 + 32);
            }
            __builtin_amdgcn_sched_barrier(0);   // pin: B group before A group
            if (kt < 10) {
#pragma unroll
                for (int p = 0; p < 4; ++p) STAGEA((kt + 2) & 3, kt + 2, p);
            }
            // boundary: retire A(kt+1) (oldest 4); keep B(kt+1)+A(kt+2) in flight
            if (kt < 10) { asm volatile("s_waitcnt vmcnt(12)" ::: "memory"); }
            else         { asm volatile("s_waitcnt vmcnt(8)"  ::: "memory"); }
            __builtin_amdgcn_s_barrier();
            __builtin_amdgcn_sched_barrier(0);
        }
    }
#undef STAGEA

    // ---- coalesced epilogue: per-wave LDS staging (reuses SMEM) ----
    __syncthreads();
    float* Cs = (float*)SMEM + w * (16 * 68);   // 4352 B per wave
    float bvj[4];
#pragma unroll
    for (int j = 0; j < 4; ++j) bvj[j] = bias[n0 + wn * 64 + j * 16 + l15];

#pragma unroll
    for (int i = 0; i < 8; ++i) {
        __builtin_amdgcn_sched_barrier(0);   // wave-local WAR vs prev iter reads
#pragma unroll
        for (int j = 0; j < 4; ++j)
#pragma unroll
            for (int r = 0; r < 4; ++r)
                Cs[(quad * 4 + r) * 68 + j * 16 + l15] = acc[i][j][r] + bvj[j];
        __builtin_amdgcn_sched_barrier(0);
        asm volatile("s_waitcnt lgkmcnt(0)" ::: "memory");
        if constexpr (OUT_BF16) {
#pragma unroll
            for (int p = 0; p < 2; ++p) {
                const int row = p * 8 + (lane >> 3);
                const int c0 = (lane & 7) * 8;
                float4 a = *(const float4*)&Cs[row * 68 + c0];
                float4 bb = *(const float4*)&Cs[row * 68 + c0 + 4];
                u16x8 pk;
                pk[0] = f2bf(a.x); pk[1] = f2bf(a.y); pk[2] = f2bf(a.z); pk[3] = f2bf(a.w);
                pk[4] = f2bf(bb.x); pk[5] = f2bf(bb.y); pk[6] = f2bf(bb.z); pk[7] = f2bf(bb.w);
                *(u16x8*)((unsigned short*)C +
                          (size_t)(m0 + wm * 128 + i * 16 + row) * Ncols + n0 + wn * 64 + c0) = pk;
            }
        } else {
#pragma unroll
            for (int p = 0; p < 4; ++p) {
                const int row = p * 4 + (lane >> 4);
                const int c0 = (lane & 15) * 4;
                float4 a = *(const float4*)&Cs[row * 68 + c0];
                *(float4*)((float*)C +
                           (size_t)(m0 + wm * 128 + i * 16 + row) * Ncols + n0 + wn * 64 + c0) = a;
            }
        }
        __builtin_amdgcn_sched_barrier(0);
    }
}

// ---------------------------------------------------------------------------
// attention v4 = v3 + coalesced ctx stores.
// One block per (b,h), 4 waves, wave w owns Q-tiles {w, w+4, ...}.
// S^T via mfma(kf,qf); softmax row per lane; shuffle-built PV A-frags.
// K in Ks[208][72] (conflict-free b128), V in swizzled Vt[64][256].
// ctx stores staged through per-wave Os[16][72] bf16 -> b128 full-line stores
// (wave-local DS ordering: in-order DS unit + sched_barrier + lgkmcnt(0);
//  __syncthreads is NOT usable here - waves have unequal tile counts).
// LDS = 71936 B -> 2 blocks/CU.
// ---------------------------------------------------------------------------
__global__ __launch_bounds__(256, 2) void attn_kernel(
    const unsigned short* __restrict__ QKV,
    const float* __restrict__ pos_bias,
    const int* __restrict__ mask,
    unsigned short* __restrict__ ctx)
{
    __shared__ __align__(16) unsigned short Ks[208 * 72];     // 29952 B
    __shared__ __align__(16) unsigned short Vt[64 * 256];     // 32768 B
    __shared__ __align__(16) unsigned short Os[4][16 * 72];   //  9216 B
    const int b = blockIdx.x / HEADS, h = blockIdx.x % HEADS;
    const int t = threadIdx.x, w = t >> 6, lane = t & 63;
    const int quad = lane >> 4, l15 = lane & 15;
    const size_t base = (size_t)b * SEQ * QKV_N + h * HEAD_DIM;

    // ---- stage K rows 0..195 (b128 in, b128 out), zero rows 196..207
    for (int c = t; c < SEQ * 8; c += 256) {
        int row = c >> 3, d0 = (c & 7) * 8;
        *(bf16x8*)(Ks + row * 72 + d0) =
            *(const bf16x8*)(QKV + base + (size_t)row * QKV_N + HIDDEN + d0);
    }
    {
        bf16x8 z = {};
        for (int i = t; i < 12 * 9; i += 256) {
            int row = 196 + i / 9, d0 = (i % 9) * 8;
            *(bf16x8*)(Ks + row * 72 + d0) = z;
        }
    }
    // ---- zero Vt pad keys 196..255 (swizzled addresses)
    for (int i = t; i < 64 * 60; i += 256) {
        int row = i / 60, key = 196 + i % 60;
        int s = (row & 7) ^ ((row >> 3) & 7);
        Vt[row * 256 + ((((key >> 3) ^ s) << 3) | (key & 7))] = 0;
    }
    // ---- stage V transposed + swizzled: Vt[d][key'] = V[key][d]
    for (int c = t; c < SEQ * 8; c += 256) {
        int key = c >> 3, d0 = (c & 7) * 8;
        bf16x8 vv = *(const bf16x8*)(QKV + base + (size_t)key * QKV_N + 2 * HIDDEN + d0);
        int cb = key >> 3, kk = key & 7;
#pragma unroll
        for (int j = 0; j < 8; ++j) {
            int row = d0 + j;
            int s = (row & 7) ^ ((row >> 3) & 7);
            Vt[row * 256 + (((cb ^ s) << 3) | kk)] = (unsigned short)vv[j];
        }
    }
    __syncthreads();

    // per-lane swizzle constants for vf reads: rows rr = nt*16 + l15
    int vs[4];
#pragma unroll
    for (int nt = 0; nt < 4; ++nt) {
        int rr = nt * 16 + l15;
        vs[nt] = (rr & 7) ^ ((rr >> 3) & 7);
    }

    for (int t16 = w; t16 < 13; t16 += 4) {
        const int qrow = min(t16 * 16 + l15, SEQ - 1);
        const unsigned short* qp = QKV + base + (size_t)qrow * QKV_N + quad * 8;
        bf16x8 qf0 = *(const bf16x8*)(qp);
        bf16x8 qf1 = *(const bf16x8*)(qp + 32);

        f32x4 accT[13];
#pragma unroll
        for (int jt = 0; jt < 13; ++jt) {
            const unsigned short* kp = Ks + (jt * 16 + l15) * 72 + quad * 8;
            bf16x8 kf0 = *(const bf16x8*)(kp);
            bf16x8 kf1 = *(const bf16x8*)(kp + 32);
            f32x4 z = {};
            z = __builtin_amdgcn_mfma_f32_16x16x32_bf16(kf0, qf0, z, 0, 0, 0);
            z = __builtin_amdgcn_mfma_f32_16x16x32_bf16(kf1, qf1, z, 0, 0, 0);
            accT[jt] = z;  // S^T: lane l15 = q-row, key = jt*16 + quad*4 + r
        }

        // bias + mask + softmax (full attention row per lane)
        float mx = -3e38f;
#pragma unroll
        for (int jt = 0; jt < 13; ++jt) {
            const int key0 = jt * 16 + quad * 4;
            const int kb = min(key0, SEQ - 4);  // clamp float4/int4 base to 192
            float4 pb = *(const float4*)(pos_bias + (size_t)qrow * SEQ + kb);
            int4 mk = *(const int4*)(mask + b * SEQ + kb);
#pragma unroll
            for (int r = 0; r < 4; ++r) {
                const int key = key0 + r;
                const bool cv = (key < SEQ) && ((&mk.x)[r] != 0);
                float v = cv ? (accT[jt][r] * 0.125f + (&pb.x)[r]) : -1e30f;
                accT[jt][r] = v;
                mx = fmaxf(mx, v);
            }
        }
        mx = fmaxf(mx, __shfl_xor(mx, 16, 64));
        mx = fmaxf(mx, __shfl_xor(mx, 32, 64));
        float sm = 0.f;
#pragma unroll
        for (int jt = 0; jt < 13; ++jt)
#pragma unroll
            for (int r = 0; r < 4; ++r) {
                float e = __expf(accT[jt][r] - mx);
                accT[jt][r] = e;
                sm += e;
            }
        sm += __shfl_xor(sm, 16, 64);
        sm += __shfl_xor(sm, 32, 64);
        const float inv = 1.0f / sm;

        // pack P rows to bf16 pairs; tile 13 (keys 208..223) = 0
        unsigned int pk[14][2];
#pragma unroll
        for (int jt = 0; jt < 13; ++jt)
#pragma unroll
            for (int pp = 0; pp < 2; ++pp) {
                unsigned int lo = f2bf(accT[jt][2 * pp] * inv);
                unsigned int hi = f2bf(accT[jt][2 * pp + 1] * inv);
                pk[jt][pp] = (hi << 16) | lo;
            }
        pk[13][0] = 0; pk[13][1] = 0;

        // PV: A-frag lane l15 = q-row; k = quad*8 + j over 32-key chunks.
        f32x4 o[4] = {};
        const int hi_half = quad >> 1;
        const int sq0 = (quad & 1) * 2 * 16 + l15;   // src lane, u<2
        const int sq1 = sq0 + 16;                    // src lane, u>=2
#pragma unroll
        for (int kt = 0; kt < 7; ++kt) {
            union { unsigned int u[4]; bf16x8 v; } pf;
#pragma unroll
            for (int u = 0; u < 4; ++u) {
                const int src = (u < 2) ? sq0 : sq1;
                unsigned int a0 = (unsigned int)__shfl((int)pk[2 * kt][u & 1], src, 64);
                unsigned int a1 = (unsigned int)__shfl((int)pk[2 * kt + 1][u & 1], src, 64);
                pf.u[u] = hi_half ? a1 : a0;
            }
#pragma unroll
            for (int nt = 0; nt < 4; ++nt) {
                const int rr = nt * 16 + l15;
                const bf16x8 vf = *(const bf16x8*)(
                    &Vt[rr * 256 + (((kt * 4 + quad) ^ vs[nt]) << 3)]);
                o[nt] = __builtin_amdgcn_mfma_f32_16x16x32_bf16(pf.v, vf, o[nt], 0, 0, 0);
            }
        }

        // ---- coalesced ctx store: stage through per-wave Os, then b128 ----
        __builtin_amdgcn_sched_barrier(0);
#pragma unroll
        for (int nt = 0; nt < 4; ++nt)
#pragma unroll
            for (int r = 0; r < 4; ++r)
                Os[w][(quad * 4 + r) * 72 + nt * 16 + l15] = f2bf(o[nt][r]);
        __builtin_amdgcn_sched_barrier(0);
        asm volatile("s_waitcnt lgkmcnt(0)" ::: "memory");
#pragma unroll
        for (int p = 0; p < 2; ++p) {
            const int row = p * 8 + (lane >> 3);
            const int grow = t16 * 16 + row;
            const int c0 = (lane & 7) * 8;
            bf16x8 ov = *(const bf16x8*)&Os[w][row * 72 + c0];
            if (grow < SEQ)
                *(bf16x8*)(ctx + ((size_t)b * SEQ + grow) * HIDDEN + h * HEAD_DIM + c0) = ov;
        }
        __builtin_amdgcn_sched_barrier(0);
    }
}

// ---------------------------------------------------------------------------
extern "C" void kernel_launch(void* const* d_in, const int* in_sizes, int n_in,
                              void* d_out, int out_size, void* d_ws, size_t ws_size,
                              hipStream_t stream) {
    const float* x    = (const float*)d_in[0];
    const float* Wq   = (const float*)d_in[1];
    const float* bq   = (const float*)d_in[2];
    const float* Wk   = (const float*)d_in[3];
    const float* bk   = (const float*)d_in[4];
    const float* Wv   = (const float*)d_in[5];
    const float* bv   = (const float*)d_in[6];
    const float* Wp   = (const float*)d_in[7];
    const float* bp   = (const float*)d_in[8];
    const float* pos  = (const float*)d_in[9];
    const int*   mask = (const int*)d_in[10];

    char* ws = (char*)d_ws;
    size_t off = 0;
    auto alloc = [&](size_t bytes) -> char* {
        char* p = ws + off;
        off += (bytes + 255) & ~(size_t)255;
        return p;
    };
    unsigned short* xb    = (unsigned short*)alloc((size_t)M_TOT * HIDDEN * 2);
    unsigned short* wqkv  = (unsigned short*)alloc((size_t)QKV_N * HIDDEN * 2);
    unsigned short* wpb   = (unsigned short*)alloc((size_t)HIDDEN * HIDDEN * 2);
    float*          biasq = (float*)alloc((size_t)QKV_N * 4);
    unsigned short* qkv   = (unsigned short*)alloc((size_t)M_TOT * QKV_N * 2);
    unsigned short* ctx   = (unsigned short*)alloc((size_t)M_TOT * HIDDEN * 2);

    prep_kernel<<<21123, 256, 0, stream>>>(x, Wq, Wk, Wv, Wp, bq, bk, bv,
                                           xb, wqkv, wpb, biasq);
    gemm256<true><<<dim3(QKV_N / 256, M_TOT / 256), 512, 0, stream>>>(
        xb, wqkv, biasq, (void*)qkv, QKV_N);
    attn_kernel<<<BATCH * HEADS, 256, 0, stream>>>(qkv, pos, mask, ctx);
    gemm256<false><<<dim3(HIDDEN / 256, M_TOT / 256), 512, 0, stream>>>(
        ctx, wpb, bp, d_out, HIDDEN);
}

// Round 4
// 363.445 us; speedup vs baseline: 1.1497x; 1.1497x over previous
//
#include <hip/hip_runtime.h>
#include <hip/hip_bf16.h>

#define HIDDEN 768
#define HEADS 12
#define HEAD_DIM 64
#define BATCH 128
#define SEQ 196
#define M_TOT (BATCH * SEQ)   /* 25088 */
#define QKV_N (3 * HIDDEN)    /* 2304  */

typedef __attribute__((ext_vector_type(8))) short bf16x8;
typedef __attribute__((ext_vector_type(8))) unsigned short u16x8;
typedef __attribute__((ext_vector_type(4))) float f32x4;

// round-to-nearest-even f32 -> bf16 (bit pattern)
__device__ __forceinline__ unsigned short f2bf(float f) {
    unsigned int u = __builtin_bit_cast(unsigned int, f);
    unsigned int r = (u + 0x7fffu + ((u >> 16) & 1u)) >> 16;
    return (unsigned short)r;
}

__device__ __forceinline__ ushort4 cvt4(float4 v) {
    ushort4 o;
    o.x = f2bf(v.x); o.y = f2bf(v.y); o.z = f2bf(v.z); o.w = f2bf(v.w);
    return o;
}

// ---------------------------------------------------------------------------
// prep: cast x -> bf16; build fused Wqkv [2304,768] bf16 (rows: Wq|Wk|Wv);
// cast Wp -> bf16; fuse biases [2304] f32.
// ---------------------------------------------------------------------------
__global__ __launch_bounds__(256) void prep_kernel(
    const float* __restrict__ x,
    const float* __restrict__ Wq, const float* __restrict__ Wk,
    const float* __restrict__ Wv, const float* __restrict__ Wp,
    const float* __restrict__ bq, const float* __restrict__ bk,
    const float* __restrict__ bv,
    unsigned short* __restrict__ xb, unsigned short* __restrict__ wqkv,
    unsigned short* __restrict__ wpb, float* __restrict__ biasq)
{
    const long long NX = (long long)M_TOT * HIDDEN / 4;        // 4816896
    const long long NQ = NX + (long long)QKV_N * HIDDEN / 4;   // +442368
    const long long NP = NQ + (long long)HIDDEN * HIDDEN / 4;  // +147456
    const long long NB = NP + QKV_N / 4;                       // +576
    long long tid = (long long)blockIdx.x * 256 + threadIdx.x;
    if (tid < NX) {
        float4 v = ((const float4*)x)[tid];
        ((ushort4*)xb)[tid] = cvt4(v);
    } else if (tid < NQ) {
        int i = (int)(tid - NX);
        int e = i * 4;
        int row = e / HIDDEN, col = e % HIDDEN;
        const float* s = (row < HIDDEN) ? (Wq + (size_t)row * HIDDEN + col)
                       : (row < 2 * HIDDEN) ? (Wk + (size_t)(row - HIDDEN) * HIDDEN + col)
                       : (Wv + (size_t)(row - 2 * HIDDEN) * HIDDEN + col);
        ((ushort4*)wqkv)[i] = cvt4(*(const float4*)s);
    } else if (tid < NP) {
        int i = (int)(tid - NQ);
        ((ushort4*)wpb)[i] = cvt4(((const float4*)Wp)[i]);
    } else if (tid < NB) {
        int i = (int)(tid - NP);
        int e = i * 4;
        const float* s = (e < HIDDEN) ? (bq + e)
                       : (e < 2 * HIDDEN) ? (bk + (e - HIDDEN))
                       : (bv + (e - 2 * HIDDEN));
        *(float4*)(biasq + e) = *(const float4*)s;
    }
}

// ---------------------------------------------------------------------------
// gemm v4: 128x256 tile, BK=32, 8 waves (2M x 4N), wave tile 64x64, acc[4][4].
// C[M,Ncols] = A[M,768] * B[Ncols,768]^T + bias.
//
// Design (from R3 post-mortem: R1 was latency/barrier-bound at 1 block/CU,
// not DS-bound; v3's col-major chunking wrecked L2 (FETCH 80->177MB)):
//  * 2 BLOCKS PER CU: LDS 72 KB (A 3x8KB + B 3x16KB triple-buffered),
//    acc[4][4]=64 VGPR, __launch_bounds__(512,4) caps VGPR at 128.
//    Independent blocks fill each other's barrier/wait bubbles.
//  * A and B both staged via global_load_lds (R1's verified-good locality;
//    row-major XCD chunking, FETCH was 80 MB).
//  * Triple buffering => staging(kt+2) never collides with reads of kt or
//    kt+1 => ONE barrier + one lgkm0 + one counted vmcnt(3) per K-tile
//    (24/block vs R1's 96). Race safety: reads of buf b are lgkm0-complete
//    before the post-tile barrier; buf b is only rewritten (as kt+2, since
//    (kt+2)%3==(kt-1)%3) by waves that passed that barrier; vmcnt(3) at
//    tile kt retires exactly tile (kt+1)'s 3 loads (issue-order FIFO).
//  * 2-bit XOR swizzle for 64B rows: 16B-slot ^= (row&3) -> ds_read_b128
//    lands 2 lanes/bank (free). Staging pre-swizzles the GLOBAL source,
//    LDS dest stays linear (global_load_lds constraint).
// Epilogue: per-wave LDS staging -> full-cache-line stores (R1-verified).
// ---------------------------------------------------------------------------
template <bool OUT_BF16>
__global__ __launch_bounds__(512, 4) void gemm_v4(
    const unsigned short* __restrict__ A,
    const unsigned short* __restrict__ B,
    const float* __restrict__ bias,
    void* __restrict__ C, const int Ncols)
{
    __shared__ __align__(16) unsigned short SMEM[36864];  // 72 KB
    const int t = threadIdx.x, w = t >> 6, lane = t & 63;
    const int quad = lane >> 4, l15 = lane & 15;
    const int wm = w >> 2, wn = w & 3;          // 2M x 4N waves, tile 64x64

    // ---- row-major wg linearization + bijective XCD chunking (R1 pattern)
    const int gx = gridDim.x;
    const int nwg = gx * (int)gridDim.y;
    const int orig = blockIdx.y * gx + blockIdx.x;
    const int qq = nwg >> 3, rr2 = nwg & 7;
    const int xcd = orig & 7, loc = orig >> 3;
    const int wg = (xcd < rr2 ? xcd * (qq + 1) : rr2 * (qq + 1) + (xcd - rr2) * qq) + loc;
    const int m0 = (wg / gx) * 128, n0 = (wg % gx) * 256;

    // ---- staging map: thread -> row = t>>2, 16B slot = t&3 (64B rows) ----
    const int srow = t >> 2, sslot = t & 3;
    const int ksw = (sslot ^ (srow & 3)) << 3;           // pre-swizzled k elems
    const unsigned short* Ag = A + (size_t)(m0 + srow) * HIDDEN + ksw;
    const unsigned short* Bg = B + (size_t)(n0 + srow) * HIDDEN + ksw;
    const int aw = w * 512;            // A dest (ushorts): + buf*4096
    const int bw = 12288 + w * 512;    // B dest: + buf*8192 (+4096 for p=1)

#define STAGE(kt2)  do {                                                            \
    __builtin_amdgcn_global_load_lds(                                               \
        (__attribute__((address_space(1))) void*)(Ag + (kt2) * 32),                 \
        (__attribute__((address_space(3))) void*)(SMEM + ((kt2) % 3) * 4096 + aw),  \
        16, 0, 0);                                                                  \
    __builtin_amdgcn_global_load_lds(                                               \
        (__attribute__((address_space(1))) void*)(Bg + (kt2) * 32),                 \
        (__attribute__((address_space(3))) void*)(SMEM + 12288 + ((kt2) % 3) * 8192 + w * 512), \
        16, 0, 0);                                                                  \
    __builtin_amdgcn_global_load_lds(                                               \
        (__attribute__((address_space(1))) void*)(Bg + (size_t)128 * HIDDEN + (kt2) * 32), \
        (__attribute__((address_space(3))) void*)(SMEM + 12288 + ((kt2) % 3) * 8192 + 4096 + w * 512), \
        16, 0, 0);                                                                  \
  } while (0)

    // ---- fragment read offsets (swizzled: slot = quad ^ (row&3)) ----
    const int fsw = (quad ^ (l15 & 3)) << 3;
    const int aoff = (wm * 64 + l15) * 32 + fsw;           // + buf*4096 + i*512
    const int boff = 12288 + (wn * 64 + l15) * 32 + fsw;   // + buf*8192 + j*512

    f32x4 acc[4][4] = {};

    // ---- prologue: tiles 0,1 in flight; retire tile 0 ----
    STAGE(0);
    STAGE(1);
    asm volatile("s_waitcnt vmcnt(3)" ::: "memory");
    __builtin_amdgcn_s_barrier();

    // ---- K loop: 24 tiles of BK=32, fully unrolled, 1 barrier/tile ----
#pragma unroll
    for (int kt = 0; kt < 24; ++kt) {
        const int bufA = (kt % 3) * 4096, bufB = (kt % 3) * 8192;
        if (kt < 22) STAGE(kt + 2);
        bf16x8 Af[4], Bf[4];
#pragma unroll
        for (int i = 0; i < 4; ++i)
            Af[i] = *(const bf16x8*)(SMEM + bufA + aoff + i * 512);
#pragma unroll
        for (int j = 0; j < 4; ++j)
            Bf[j] = *(const bf16x8*)(SMEM + bufB + boff + j * 512);
        asm volatile("s_waitcnt lgkmcnt(0)" ::: "memory");
        __builtin_amdgcn_sched_barrier(0);
        __builtin_amdgcn_s_setprio(1);
#pragma unroll
        for (int i = 0; i < 4; ++i)
#pragma unroll
            for (int j = 0; j < 4; ++j)
                acc[i][j] = __builtin_amdgcn_mfma_f32_16x16x32_bf16(
                    Af[i], Bf[j], acc[i][j], 0, 0, 0);
        __builtin_amdgcn_s_setprio(0);
        __builtin_amdgcn_sched_barrier(0);
        // boundary: retire tile (kt+1)'s 3 loads; keep tile (kt+2)'s in flight
        if (kt < 22)       { asm volatile("s_waitcnt vmcnt(3)" ::: "memory"); }
        else if (kt == 22) { asm volatile("s_waitcnt vmcnt(0)" ::: "memory"); }
        if (kt < 23) __builtin_amdgcn_s_barrier();
    }
#undef STAGE

    // ---- coalesced epilogue: per-wave LDS staging (reuses SMEM) ----
    __syncthreads();
    float* Cs = (float*)SMEM + w * (16 * 68);   // 4352 B per wave (34816 total)
    float bvj[4];
#pragma unroll
    for (int j = 0; j < 4; ++j) bvj[j] = bias[n0 + wn * 64 + j * 16 + l15];

#pragma unroll
    for (int i = 0; i < 4; ++i) {
        __builtin_amdgcn_sched_barrier(0);   // wave-local WAR vs prev iter reads
#pragma unroll
        for (int j = 0; j < 4; ++j)
#pragma unroll
            for (int r = 0; r < 4; ++r)
                Cs[(quad * 4 + r) * 68 + j * 16 + l15] = acc[i][j][r] + bvj[j];
        __builtin_amdgcn_sched_barrier(0);
        asm volatile("s_waitcnt lgkmcnt(0)" ::: "memory");
        if constexpr (OUT_BF16) {
#pragma unroll
            for (int p = 0; p < 2; ++p) {
                const int row = p * 8 + (lane >> 3);
                const int c0 = (lane & 7) * 8;
                float4 a = *(const float4*)&Cs[row * 68 + c0];
                float4 bb = *(const float4*)&Cs[row * 68 + c0 + 4];
                u16x8 pk;
                pk[0] = f2bf(a.x); pk[1] = f2bf(a.y); pk[2] = f2bf(a.z); pk[3] = f2bf(a.w);
                pk[4] = f2bf(bb.x); pk[5] = f2bf(bb.y); pk[6] = f2bf(bb.z); pk[7] = f2bf(bb.w);
                *(u16x8*)((unsigned short*)C +
                          (size_t)(m0 + wm * 64 + i * 16 + row) * Ncols + n0 + wn * 64 + c0) = pk;
            }
        } else {
#pragma unroll
            for (int p = 0; p < 4; ++p) {
                const int row = p * 4 + (lane >> 4);
                const int c0 = (lane & 15) * 4;
                float4 a = *(const float4*)&Cs[row * 68 + c0];
                *(float4*)((float*)C +
                           (size_t)(m0 + wm * 64 + i * 16 + row) * Ncols + n0 + wn * 64 + c0) = a;
            }
        }
        __builtin_amdgcn_sched_barrier(0);
    }
}

// ---------------------------------------------------------------------------
// attention v4 = v3 + coalesced ctx stores.
// One block per (b,h), 4 waves, wave w owns Q-tiles {w, w+4, ...}.
// S^T via mfma(kf,qf); softmax row per lane; shuffle-built PV A-frags.
// K in Ks[208][72] (conflict-free b128), V in swizzled Vt[64][256].
// ctx stores staged through per-wave Os[16][72] bf16 -> b128 full-line stores
// (wave-local DS ordering: in-order DS unit + sched_barrier + lgkmcnt(0);
//  __syncthreads is NOT usable here - waves have unequal tile counts).
// LDS = 71936 B -> 2 blocks/CU.
// ---------------------------------------------------------------------------
__global__ __launch_bounds__(256, 2) void attn_kernel(
    const unsigned short* __restrict__ QKV,
    const float* __restrict__ pos_bias,
    const int* __restrict__ mask,
    unsigned short* __restrict__ ctx)
{
    __shared__ __align__(16) unsigned short Ks[208 * 72];     // 29952 B
    __shared__ __align__(16) unsigned short Vt[64 * 256];     // 32768 B
    __shared__ __align__(16) unsigned short Os[4][16 * 72];   //  9216 B
    const int b = blockIdx.x / HEADS, h = blockIdx.x % HEADS;
    const int t = threadIdx.x, w = t >> 6, lane = t & 63;
    const int quad = lane >> 4, l15 = lane & 15;
    const size_t base = (size_t)b * SEQ * QKV_N + h * HEAD_DIM;

    // ---- stage K rows 0..195 (b128 in, b128 out), zero rows 196..207
    for (int c = t; c < SEQ * 8; c += 256) {
        int row = c >> 3, d0 = (c & 7) * 8;
        *(bf16x8*)(Ks + row * 72 + d0) =
            *(const bf16x8*)(QKV + base + (size_t)row * QKV_N + HIDDEN + d0);
    }
    {
        bf16x8 z = {};
        for (int i = t; i < 12 * 9; i += 256) {
            int row = 196 + i / 9, d0 = (i % 9) * 8;
            *(bf16x8*)(Ks + row * 72 + d0) = z;
        }
    }
    // ---- zero Vt pad keys 196..255 (swizzled addresses)
    for (int i = t; i < 64 * 60; i += 256) {
        int row = i / 60, key = 196 + i % 60;
        int s = (row & 7) ^ ((row >> 3) & 7);
        Vt[row * 256 + ((((key >> 3) ^ s) << 3) | (key & 7))] = 0;
    }
    // ---- stage V transposed + swizzled: Vt[d][key'] = V[key][d]
    for (int c = t; c < SEQ * 8; c += 256) {
        int key = c >> 3, d0 = (c & 7) * 8;
        bf16x8 vv = *(const bf16x8*)(QKV + base + (size_t)key * QKV_N + 2 * HIDDEN + d0);
        int cb = key >> 3, kk = key & 7;
#pragma unroll
        for (int j = 0; j < 8; ++j) {
            int row = d0 + j;
            int s = (row & 7) ^ ((row >> 3) & 7);
            Vt[row * 256 + (((cb ^ s) << 3) | kk)] = (unsigned short)vv[j];
        }
    }
    __syncthreads();

    // per-lane swizzle constants for vf reads: rows rr = nt*16 + l15
    int vs[4];
#pragma unroll
    for (int nt = 0; nt < 4; ++nt) {
        int rr = nt * 16 + l15;
        vs[nt] = (rr & 7) ^ ((rr >> 3) & 7);
    }

    for (int t16 = w; t16 < 13; t16 += 4) {
        const int qrow = min(t16 * 16 + l15, SEQ - 1);
        const unsigned short* qp = QKV + base + (size_t)qrow * QKV_N + quad * 8;
        bf16x8 qf0 = *(const bf16x8*)(qp);
        bf16x8 qf1 = *(const bf16x8*)(qp + 32);

        f32x4 accT[13];
#pragma unroll
        for (int jt = 0; jt < 13; ++jt) {
            const unsigned short* kp = Ks + (jt * 16 + l15) * 72 + quad * 8;
            bf16x8 kf0 = *(const bf16x8*)(kp);
            bf16x8 kf1 = *(const bf16x8*)(kp + 32);
            f32x4 z = {};
            z = __builtin_amdgcn_mfma_f32_16x16x32_bf16(kf0, qf0, z, 0, 0, 0);
            z = __builtin_amdgcn_mfma_f32_16x16x32_bf16(kf1, qf1, z, 0, 0, 0);
            accT[jt] = z;  // S^T: lane l15 = q-row, key = jt*16 + quad*4 + r
        }

        // bias + mask + softmax (full attention row per lane)
        float mx = -3e38f;
#pragma unroll
        for (int jt = 0; jt < 13; ++jt) {
            const int key0 = jt * 16 + quad * 4;
            const int kb = min(key0, SEQ - 4);  // clamp float4/int4 base to 192
            float4 pb = *(const float4*)(pos_bias + (size_t)qrow * SEQ + kb);
            int4 mk = *(const int4*)(mask + b * SEQ + kb);
#pragma unroll
            for (int r = 0; r < 4; ++r) {
                const int key = key0 + r;
                const bool cv = (key < SEQ) && ((&mk.x)[r] != 0);
                float v = cv ? (accT[jt][r] * 0.125f + (&pb.x)[r]) : -1e30f;
                accT[jt][r] = v;
                mx = fmaxf(mx, v);
            }
        }
        mx = fmaxf(mx, __shfl_xor(mx, 16, 64));
        mx = fmaxf(mx, __shfl_xor(mx, 32, 64));
        float sm = 0.f;
#pragma unroll
        for (int jt = 0; jt < 13; ++jt)
#pragma unroll
            for (int r = 0; r < 4; ++r) {
                float e = __expf(accT[jt][r] - mx);
                accT[jt][r] = e;
                sm += e;
            }
        sm += __shfl_xor(sm, 16, 64);
        sm += __shfl_xor(sm, 32, 64);
        const float inv = 1.0f / sm;

        // pack P rows to bf16 pairs; tile 13 (keys 208..223) = 0
        unsigned int pk[14][2];
#pragma unroll
        for (int jt = 0; jt < 13; ++jt)
#pragma unroll
            for (int pp = 0; pp < 2; ++pp) {
                unsigned int lo = f2bf(accT[jt][2 * pp] * inv);
                unsigned int hi = f2bf(accT[jt][2 * pp + 1] * inv);
                pk[jt][pp] = (hi << 16) | lo;
            }
        pk[13][0] = 0; pk[13][1] = 0;

        // PV: A-frag lane l15 = q-row; k = quad*8 + j over 32-key chunks.
        f32x4 o[4] = {};
        const int hi_half = quad >> 1;
        const int sq0 = (quad & 1) * 2 * 16 + l15;   // src lane, u<2
        const int sq1 = sq0 + 16;                    // src lane, u>=2
#pragma unroll
        for (int kt = 0; kt < 7; ++kt) {
            union { unsigned int u[4]; bf16x8 v; } pf;
#pragma unroll
            for (int u = 0; u < 4; ++u) {
                const int src = (u < 2) ? sq0 : sq1;
                unsigned int a0 = (unsigned int)__shfl((int)pk[2 * kt][u & 1], src, 64);
                unsigned int a1 = (unsigned int)__shfl((int)pk[2 * kt + 1][u & 1], src, 64);
                pf.u[u] = hi_half ? a1 : a0;
            }
#pragma unroll
            for (int nt = 0; nt < 4; ++nt) {
                const int rr = nt * 16 + l15;
                const bf16x8 vf = *(const bf16x8*)(
                    &Vt[rr * 256 + (((kt * 4 + quad) ^ vs[nt]) << 3)]);
                o[nt] = __builtin_amdgcn_mfma_f32_16x16x32_bf16(pf.v, vf, o[nt], 0, 0, 0);
            }
        }

        // ---- coalesced ctx store: stage through per-wave Os, then b128 ----
        __builtin_amdgcn_sched_barrier(0);
#pragma unroll
        for (int nt = 0; nt < 4; ++nt)
#pragma unroll
            for (int r = 0; r < 4; ++r)
                Os[w][(quad * 4 + r) * 72 + nt * 16 + l15] = f2bf(o[nt][r]);
        __builtin_amdgcn_sched_barrier(0);
        asm volatile("s_waitcnt lgkmcnt(0)" ::: "memory");
#pragma unroll
        for (int p = 0; p < 2; ++p) {
            const int row = p * 8 + (lane >> 3);
            const int grow = t16 * 16 + row;
            const int c0 = (lane & 7) * 8;
            bf16x8 ov = *(const bf16x8*)&Os[w][row * 72 + c0];
            if (grow < SEQ)
                *(bf16x8*)(ctx + ((size_t)b * SEQ + grow) * HIDDEN + h * HEAD_DIM + c0) = ov;
        }
        __builtin_amdgcn_sched_barrier(0);
    }
}

// ---------------------------------------------------------------------------
extern "C" void kernel_launch(void* const* d_in, const int* in_sizes, int n_in,
                              void* d_out, int out_size, void* d_ws, size_t ws_size,
                              hipStream_t stream) {
    const float* x    = (const float*)d_in[0];
    const float* Wq   = (const float*)d_in[1];
    const float* bq   = (const float*)d_in[2];
    const float* Wk   = (const float*)d_in[3];
    const float* bk   = (const float*)d_in[4];
    const float* Wv   = (const float*)d_in[5];
    const float* bv   = (const float*)d_in[6];
    const float* Wp   = (const float*)d_in[7];
    const float* bp   = (const float*)d_in[8];
    const float* pos  = (const float*)d_in[9];
    const int*   mask = (const int*)d_in[10];

    char* ws = (char*)d_ws;
    size_t off = 0;
    auto alloc = [&](size_t bytes) -> char* {
        char* p = ws + off;
        off += (bytes + 255) & ~(size_t)255;
        return p;
    };
    unsigned short* xb    = (unsigned short*)alloc((size_t)M_TOT * HIDDEN * 2);
    unsigned short* wqkv  = (unsigned short*)alloc((size_t)QKV_N * HIDDEN * 2);
    unsigned short* wpb   = (unsigned short*)alloc((size_t)HIDDEN * HIDDEN * 2);
    float*          biasq = (float*)alloc((size_t)QKV_N * 4);
    unsigned short* qkv   = (unsigned short*)alloc((size_t)M_TOT * QKV_N * 2);
    unsigned short* ctx   = (unsigned short*)alloc((size_t)M_TOT * HIDDEN * 2);

    prep_kernel<<<21123, 256, 0, stream>>>(x, Wq, Wk, Wv, Wp, bq, bk, bv,
                                           xb, wqkv, wpb, biasq);
    gemm_v4<true><<<dim3(QKV_N / 256, M_TOT / 128), 512, 0, stream>>>(
        xb, wqkv, biasq, (void*)qkv, QKV_N);
    attn_kernel<<<BATCH * HEADS, 256, 0, stream>>>(qkv, pos, mask, ctx);
    gemm_v4<false><<<dim3(HIDDEN / 256, M_TOT / 128), 512, 0, stream>>>(
        ctx, wpb, bp, d_out, HIDDEN);
}